// Round 1
// baseline (1328.770 us; speedup 1.0000x reference)
//
#include <hip/hip_runtime.h>
#include <hip/hip_bf16.h>

typedef float f32x4 __attribute__((ext_vector_type(4)));
typedef __bf16 bf16x8 __attribute__((ext_vector_type(8)));

#define BM 128
#define BN 128
#define BK 64
#define LDK 72  // padded LDS row stride (144 B = 16B-aligned, spreads banks: 2-way max = free)

// ---------------- query: q[b,h] = sum_e dec[b,e] * Wq[h,e] ----------------
__global__ __launch_bounds__(256) void query_kernel(const float* __restrict__ dec,
                                                    const float* __restrict__ Wq,
                                                    float* __restrict__ q) {
  int wid = threadIdx.x >> 6, lane = threadIdx.x & 63;
  int o = blockIdx.x * 4 + wid;  // 0..32767
  int b = o >> 10, h = o & 1023;
  const float* wrow = Wq + (size_t)h * 1024;
  const float* drow = dec + (size_t)b * 1024;
  float s = 0.f;
#pragma unroll
  for (int j = 0; j < 4; ++j) {
    int e = j * 256 + lane * 4;
    float4 w = *(const float4*)(wrow + e);
    float4 d = *(const float4*)(drow + e);
    s += w.x * d.x + w.y * d.y + w.z * d.z + w.w * d.w;
  }
  for (int off = 32; off; off >>= 1) s += __shfl_xor(s, off);
  if (lane == 0) q[o] = s;
}

__device__ inline float fast_tanh(float x) {
  x = fminf(fmaxf(x, -15.f), 15.f);
  float e = __expf(2.f * x);
  return (e - 1.f) / (e + 1.f);
}

__device__ inline bf16x8 pack8(float4 a, float4 b) {
  bf16x8 r;
  r[0] = (__bf16)a.x; r[1] = (__bf16)a.y; r[2] = (__bf16)a.z; r[3] = (__bf16)a.w;
  r[4] = (__bf16)b.x; r[5] = (__bf16)b.y; r[6] = (__bf16)b.z; r[7] = (__bf16)b.w;
  return r;
}

// ---- fused: key = enc@Wk^T (bf16 MFMA), scores[m] += sum_h tanh(key+q)*We[h] ----
// A = enc [M=65536, K=2048] fp32 row-major; B = Wk [N=1024, K=2048] fp32 row-major (NT gemm)
__global__ __launch_bounds__(256) void key_score_kernel(
    const float* __restrict__ enc, const float* __restrict__ Wk,
    const float* __restrict__ q, const float* __restrict__ We,
    float* __restrict__ scores) {
  __shared__ __align__(16) __bf16 As[BM][LDK];
  __shared__ __align__(16) __bf16 Bs[BN][LDK];
  __shared__ float qs[BN], wes[BN];

  const int t = threadIdx.x;
  const int nblk = blockIdx.x & 7;   // N/BN = 8 (fast dim: consecutive blocks share A panel)
  const int mblk = blockIdx.x >> 3;  // 512
  const int mbase = mblk * BM;
  const int nbase = nblk * BN;
  const int b = mbase >> 11;  // S=2048 -> whole block is one batch row

  if (t < BN) {
    qs[t] = q[(b << 10) + nbase + t];
    wes[t] = We[nbase + t];
  }

  const int lane = t & 63;
  const int wid = t >> 6;
  const int wm = (wid >> 1) * 64;
  const int wn = (wid & 1) * 64;

  // staging map: thread t -> rows (t>>3)+32*i, 8-float chunk (t&7)*8
  const int srow = t >> 3;
  const int scol = (t & 7) * 8;
  const float* Ag = enc + (size_t)(mbase + srow) * 2048 + scol;
  const float* Bg = Wk + (size_t)(nbase + srow) * 2048 + scol;

  f32x4 acc[4][4] = {};

  for (int kt = 0; kt < 2048; kt += BK) {
    float4 av[4][2], bv[4][2];
#pragma unroll
    for (int i = 0; i < 4; ++i) {
      const float* pa = Ag + kt + (size_t)(i * 32) * 2048;
      const float* pb = Bg + kt + (size_t)(i * 32) * 2048;
      av[i][0] = *(const float4*)pa;
      av[i][1] = *(const float4*)(pa + 4);
      bv[i][0] = *(const float4*)pb;
      bv[i][1] = *(const float4*)(pb + 4);
    }
    __syncthreads();  // prev iteration's ds_reads complete before overwrite
#pragma unroll
    for (int i = 0; i < 4; ++i) {
      int r = srow + i * 32;
      *(bf16x8*)&As[r][scol] = pack8(av[i][0], av[i][1]);
      *(bf16x8*)&Bs[r][scol] = pack8(bv[i][0], bv[i][1]);
    }
    __syncthreads();
#pragma unroll
    for (int ks = 0; ks < 2; ++ks) {
      const int k0 = ks * 32 + ((lane >> 4) << 3);
      bf16x8 af[4], bf[4];
#pragma unroll
      for (int m = 0; m < 4; ++m)
        af[m] = *(const bf16x8*)&As[wm + m * 16 + (lane & 15)][k0];
#pragma unroll
      for (int n = 0; n < 4; ++n)
        bf[n] = *(const bf16x8*)&Bs[wn + n * 16 + (lane & 15)][k0];
#pragma unroll
      for (int m = 0; m < 4; ++m)
#pragma unroll
        for (int n = 0; n < 4; ++n)
          acc[m][n] = __builtin_amdgcn_mfma_f32_16x16x32_bf16(af[m], bf[n], acc[m][n], 0, 0, 0);
    }
  }

  // epilogue: C/D layout (verified m89/m91): col = lane&15, row = (lane>>4)*4 + reg
  const int cgrp = lane >> 4;
  const int clane = lane & 15;
#pragma unroll
  for (int m = 0; m < 4; ++m) {
#pragma unroll
    for (int r = 0; r < 4; ++r) {
      const int rl = wm + m * 16 + cgrp * 4 + r;
      float p = 0.f;
#pragma unroll
      for (int n = 0; n < 4; ++n) {
        const int cl = wn + n * 16 + clane;
        float v = acc[m][n][r] + qs[cl];
        p += fast_tanh(v) * wes[cl];
      }
      // reduce across the 16 column-lanes sharing this row
      p += __shfl_xor(p, 1);
      p += __shfl_xor(p, 2);
      p += __shfl_xor(p, 4);
      p += __shfl_xor(p, 8);
      if (clane == 0) atomicAdd(&scores[mbase + rl], p);
    }
  }
}

// ---------------- softmax over S per batch row ----------------
__global__ __launch_bounds__(256) void softmax_kernel(const float* __restrict__ scores,
                                                      float* __restrict__ alphas) {
  const float* srow = scores + blockIdx.x * 2048;
  float* arow = alphas + blockIdx.x * 2048;
  int t = threadIdx.x, lane = t & 63, wid = t >> 6;
  float v[8];
  float mx = -1e30f;
#pragma unroll
  for (int i = 0; i < 8; ++i) {
    v[i] = srow[t + i * 256];
    mx = fmaxf(mx, v[i]);
  }
  for (int off = 32; off; off >>= 1) mx = fmaxf(mx, __shfl_xor(mx, off));
  __shared__ float redm[4], reds[4];
  if (lane == 0) redm[wid] = mx;
  __syncthreads();
  mx = fmaxf(fmaxf(redm[0], redm[1]), fmaxf(redm[2], redm[3]));
  float sum = 0.f;
#pragma unroll
  for (int i = 0; i < 8; ++i) {
    v[i] = __expf(v[i] - mx);
    sum += v[i];
  }
  for (int off = 32; off; off >>= 1) sum += __shfl_xor(sum, off);
  if (lane == 0) reds[wid] = sum;
  __syncthreads();
  sum = reds[0] + reds[1] + reds[2] + reds[3];
  float inv = 1.f / sum;
#pragma unroll
  for (int i = 0; i < 8; ++i) arow[t + i * 256] = v[i] * inv;
}

// ---------------- context partials: no atomics ----------------
__global__ __launch_bounds__(256) void context_partial_kernel(
    const float* __restrict__ enc, const float* __restrict__ alphas,
    float* __restrict__ partial) {
  int blk = blockIdx.x;  // 512 = 32b * 2ec * 8sc
  int sc = blk & 7;
  int ec = (blk >> 3) & 1;
  int b = blk >> 4;
  int t = threadIdx.x;
  int e0 = ec * 1024 + t * 4;
  __shared__ float al[256];
  al[t] = alphas[b * 2048 + sc * 256 + t];
  __syncthreads();
  const float* ebase = enc + (size_t)b * 2048 * 2048 + (size_t)(sc * 256) * 2048 + e0;
  f32x4 acc = {};
  for (int s = 0; s < 256; ++s) {
    float a = al[s];
    float4 v = *(const float4*)(ebase + (size_t)s * 2048);
    acc[0] += a * v.x; acc[1] += a * v.y; acc[2] += a * v.z; acc[3] += a * v.w;
  }
  *(f32x4*)(partial + ((size_t)sc * 32 + b) * 2048 + e0) = acc;
}

__global__ __launch_bounds__(256) void context_reduce_kernel(const float* __restrict__ partial,
                                                             float* __restrict__ out) {
  int i = blockIdx.x * 256 + threadIdx.x;
  float s = 0.f;
#pragma unroll
  for (int sc = 0; sc < 8; ++sc) s += partial[sc * 65536 + i];
  out[i] = s;
}

extern "C" void kernel_launch(void* const* d_in, const int* in_sizes, int n_in,
                              void* d_out, int out_size, void* d_ws, size_t ws_size,
                              hipStream_t stream) {
  const float* enc = (const float*)d_in[0];  // [32, 2048, 2048]
  const float* dec = (const float*)d_in[1];  // [32, 1, 1024]
  const float* Wq = (const float*)d_in[2];   // [1024, 1024]
  const float* Wk = (const float*)d_in[3];   // [1024, 2048]
  const float* We = (const float*)d_in[4];   // [1, 1024]
  float* out = (float*)d_out;                // [32, 1, 2048]

  float* q = (float*)d_ws;           // 32768 f32
  float* scores = q + 32768;         // 65536 f32
  float* alphas = scores + 65536;    // 65536 f32
  float* partial = alphas + 65536;   // 8*65536 f32

  hipMemsetAsync(scores, 0, 65536 * sizeof(float), stream);
  query_kernel<<<8192, 256, 0, stream>>>(dec, Wq, q);
  key_score_kernel<<<4096, 256, 0, stream>>>(enc, Wk, q, We, scores);
  softmax_kernel<<<32, 256, 0, stream>>>(scores, alphas);
  context_partial_kernel<<<512, 256, 0, stream>>>(enc, alphas, partial);
  context_reduce_kernel<<<256, 256, 0, stream>>>(partial, out);
}

// Round 2
// 1176.426 us; speedup vs baseline: 1.1295x; 1.1295x over previous
//
#include <hip/hip_runtime.h>
#include <hip/hip_bf16.h>

typedef float f32x4 __attribute__((ext_vector_type(4)));
typedef __bf16 bf16x8 __attribute__((ext_vector_type(8)));

__device__ __forceinline__ float fast_tanh(float x) {
  x = fminf(fmaxf(x, -15.f), 15.f);
  float e = __expf(2.f * x);
  return (e - 1.f) / (e + 1.f);
}

__device__ __forceinline__ bf16x8 pack8(float4 a, float4 b) {
  bf16x8 r;
  r[0] = (__bf16)a.x; r[1] = (__bf16)a.y; r[2] = (__bf16)a.z; r[3] = (__bf16)a.w;
  r[4] = (__bf16)b.x; r[5] = (__bf16)b.y; r[6] = (__bf16)b.z; r[7] = (__bf16)b.w;
  return r;
}

__device__ __forceinline__ void gload_lds16(const void* g, void* l) {
  __builtin_amdgcn_global_load_lds(
      (const __attribute__((address_space(1))) unsigned int*)g,
      (__attribute__((address_space(3))) unsigned int*)l, 16, 0, 0);
}

// ---------------- query: q[b,h] = sum_e dec[b,e] * Wq[h,e] ----------------
__global__ __launch_bounds__(256) void query_kernel(const float* __restrict__ dec,
                                                    const float* __restrict__ Wq,
                                                    float* __restrict__ q) {
  int wid = threadIdx.x >> 6, lane = threadIdx.x & 63;
  int o = blockIdx.x * 4 + wid;
  int b = o >> 10, h = o & 1023;
  const float* wrow = Wq + (size_t)h * 1024;
  const float* drow = dec + (size_t)b * 1024;
  float s = 0.f;
#pragma unroll
  for (int j = 0; j < 4; ++j) {
    int e = j * 256 + lane * 4;
    float4 w = *(const float4*)(wrow + e);
    float4 d = *(const float4*)(drow + e);
    s += w.x * d.x + w.y * d.y + w.z * d.z + w.w * d.w;
  }
  for (int off = 32; off; off >>= 1) s += __shfl_xor(s, off);
  if (lane == 0) q[o] = s;
}

// ---------------- fp32 -> bf16 streaming convert ----------------
__global__ __launch_bounds__(256) void f32_to_bf16_kernel(const float* __restrict__ in,
                                                          __bf16* __restrict__ out) {
  size_t i = ((size_t)blockIdx.x * 256 + threadIdx.x) * 8;
  float4 a = *(const float4*)(in + i);
  float4 b = *(const float4*)(in + i + 4);
  *(bf16x8*)(out + i) = pack8(a, b);
}

// ---- m97-template GEMM: key = enc@Wk^T (bf16, global_load_lds staging) ----
// fused epilogue: scores[m] += sum_h tanh(key[m,h] + q[b,h]) * We[h]
// A [65536][2048] bf16, Bw [1024][2048] bf16, both K-major.
__global__ __launch_bounds__(256) void key_score_mfma(
    const __bf16* __restrict__ A, const __bf16* __restrict__ Bw,
    const float* __restrict__ q, const float* __restrict__ We,
    float* __restrict__ scores) {
  __shared__ __align__(16) __bf16 As[128 * 32];
  __shared__ __align__(16) __bf16 Bs[128 * 32];

  const int t = threadIdx.x;
  const int lane = t & 63;
  const int wid = t >> 6;

  // XCD-bijective swizzle: 4096 blocks, 8 XCDs (round-robin bid%8).
  // XCD x owns mblks [x*64, x*64+64), iterates nblk fast -> A panel reused in
  // that XCD's L2 by 8 temporally-adjacent blocks.
  const int bid = blockIdx.x;
  const int slot = bid >> 3;
  const int mblk = (bid & 7) * 64 + (slot >> 3);
  const int nblk = slot & 7;
  const int mbase = mblk * 128;
  const int nbase = nblk * 128;
  const int bb = mbase >> 11;  // batch row (S=2048 divides mbase)

  const int wm = (wid >> 1) * 64;
  const int wn = (wid & 1) * 64;

  // Staging: per wave 2 instrs for A (16 rows each) + 2 for B. Linear LDS dest
  // (base + lane*16); XOR swizzle realized by permuting the GLOBAL source
  // chunk: slot s of row r holds global chunk s ^ ((r>>1)&3).
  const int r0 = wid * 32 + (lane >> 2);
  const int schunk = (lane & 3) ^ ((lane >> 3) & 3);  // = (lane&3) ^ ((r0>>1)&3)
  const __bf16* gA = A + (size_t)(mbase + r0) * 2048 + schunk * 8;
  const __bf16* gB = Bw + (size_t)(nbase + r0) * 2048 + schunk * 8;
  __bf16* lA = &As[wid * 1024];  // wave-uniform
  __bf16* lB = &Bs[wid * 1024];

  // read-side swizzle: chunk slot = (lane>>4) ^ ((R>>1)&3) = (lane>>4) ^ ((lane>>1)&3)
  const int cA = (((lane >> 4) ^ ((lane >> 1) & 3)) << 3);

  f32x4 acc[4][4] = {};

  for (int kt = 0; kt < 2048; kt += 32) {
    gload_lds16(gA + kt, lA);
    gload_lds16(gA + kt + 16 * 2048, lA + 512);
    gload_lds16(gB + kt, lB);
    gload_lds16(gB + kt + 16 * 2048, lB + 512);
    __syncthreads();  // drains vmcnt -> staged data visible
    bf16x8 af[4], bf[4];
#pragma unroll
    for (int m = 0; m < 4; ++m)
      af[m] = *(const bf16x8*)&As[(wm + m * 16 + (lane & 15)) * 32 + cA];
#pragma unroll
    for (int n = 0; n < 4; ++n)
      bf[n] = *(const bf16x8*)&Bs[(wn + n * 16 + (lane & 15)) * 32 + cA];
#pragma unroll
    for (int m = 0; m < 4; ++m)
#pragma unroll
      for (int n = 0; n < 4; ++n)
        acc[m][n] = __builtin_amdgcn_mfma_f32_16x16x32_bf16(af[m], bf[n], acc[m][n], 0, 0, 0);
    __syncthreads();  // reads done before next stage overwrites
  }

  // epilogue: C/D layout col = lane&15 (N), row = (lane>>4)*4 + reg (M) — verified R1
  const int cgrp = lane >> 4, clane = lane & 15;
  float qv[4], wv[4];
#pragma unroll
  for (int n = 0; n < 4; ++n) {
    int cl = nbase + wn + n * 16 + clane;
    qv[n] = q[(bb << 10) + cl];
    wv[n] = We[cl];
  }
#pragma unroll
  for (int m = 0; m < 4; ++m)
#pragma unroll
    for (int r = 0; r < 4; ++r) {
      float p = 0.f;
#pragma unroll
      for (int n = 0; n < 4; ++n)
        p += fast_tanh(acc[m][n][r] + qv[n]) * wv[n];
      p += __shfl_xor(p, 1);
      p += __shfl_xor(p, 2);
      p += __shfl_xor(p, 4);
      p += __shfl_xor(p, 8);
      if (clane == 0) atomicAdd(&scores[mbase + wm + m * 16 + cgrp * 4 + r], p);
    }
}

// ---------------- softmax over S per batch row ----------------
__global__ __launch_bounds__(256) void softmax_kernel(const float* __restrict__ scores,
                                                      float* __restrict__ alphas) {
  const float* srow = scores + blockIdx.x * 2048;
  float* arow = alphas + blockIdx.x * 2048;
  int t = threadIdx.x, lane = t & 63, wid = t >> 6;
  float v[8];
  float mx = -1e30f;
#pragma unroll
  for (int i = 0; i < 8; ++i) {
    v[i] = srow[t + i * 256];
    mx = fmaxf(mx, v[i]);
  }
  for (int off = 32; off; off >>= 1) mx = fmaxf(mx, __shfl_xor(mx, off));
  __shared__ float redm[4], reds[4];
  if (lane == 0) redm[wid] = mx;
  __syncthreads();
  mx = fmaxf(fmaxf(redm[0], redm[1]), fmaxf(redm[2], redm[3]));
  float sum = 0.f;
#pragma unroll
  for (int i = 0; i < 8; ++i) {
    v[i] = __expf(v[i] - mx);
    sum += v[i];
  }
  for (int off = 32; off; off >>= 1) sum += __shfl_xor(sum, off);
  if (lane == 0) reds[wid] = sum;
  __syncthreads();
  sum = reds[0] + reds[1] + reds[2] + reds[3];
  float inv = 1.f / sum;
#pragma unroll
  for (int i = 0; i < 8; ++i) arow[t + i * 256] = v[i] * inv;
}

// ---------------- context partials (fp32 enc, no atomics) ----------------
__global__ __launch_bounds__(256) void context_partial16_kernel(
    const float* __restrict__ enc, const float* __restrict__ alphas,
    float* __restrict__ partial) {
  int blk = blockIdx.x;  // 1024 = 32b * 2ec * 16sc
  int sc = blk & 15;
  int ec = (blk >> 4) & 1;
  int b = blk >> 5;
  int t = threadIdx.x;
  int e0 = ec * 1024 + t * 4;
  __shared__ float al[128];
  if (t < 128) al[t] = alphas[b * 2048 + sc * 128 + t];
  __syncthreads();
  const float* ebase = enc + ((size_t)b * 2048 + sc * 128) * 2048 + e0;
  f32x4 acc = {};
#pragma unroll 4
  for (int s = 0; s < 128; ++s) {
    float a = al[s];
    float4 v = *(const float4*)(ebase + (size_t)s * 2048);
    acc[0] += a * v.x; acc[1] += a * v.y; acc[2] += a * v.z; acc[3] += a * v.w;
  }
  *(f32x4*)(partial + ((size_t)sc * 32 + b) * 2048 + e0) = acc;
}

__global__ __launch_bounds__(256) void context_reduce16_kernel(const float* __restrict__ partial,
                                                               float* __restrict__ out) {
  int i = blockIdx.x * 256 + threadIdx.x;
  float s = 0.f;
#pragma unroll
  for (int sc = 0; sc < 16; ++sc) s += partial[sc * 65536 + i];
  out[i] = s;
}

// ================== FALLBACK (round-1) path, used only if ws too small ==================
#define BM 128
#define BN 128
#define BK 64
#define LDK 72

__global__ __launch_bounds__(256) void key_score_kernel_fb(
    const float* __restrict__ enc, const float* __restrict__ Wk,
    const float* __restrict__ q, const float* __restrict__ We,
    float* __restrict__ scores) {
  __shared__ __align__(16) __bf16 As[BM][LDK];
  __shared__ __align__(16) __bf16 Bs[BN][LDK];
  __shared__ float qs[BN], wes[BN];

  const int t = threadIdx.x;
  const int nblk = blockIdx.x & 7;
  const int mblk = blockIdx.x >> 3;
  const int mbase = mblk * BM;
  const int nbase = nblk * BN;
  const int b = mbase >> 11;

  if (t < BN) {
    qs[t] = q[(b << 10) + nbase + t];
    wes[t] = We[nbase + t];
  }

  const int lane = t & 63;
  const int wid = t >> 6;
  const int wm = (wid >> 1) * 64;
  const int wn = (wid & 1) * 64;

  const int srow = t >> 3;
  const int scol = (t & 7) * 8;
  const float* Ag = enc + (size_t)(mbase + srow) * 2048 + scol;
  const float* Bg = Wk + (size_t)(nbase + srow) * 2048 + scol;

  f32x4 acc[4][4] = {};

  for (int kt = 0; kt < 2048; kt += BK) {
    float4 av[4][2], bv[4][2];
#pragma unroll
    for (int i = 0; i < 4; ++i) {
      const float* pa = Ag + kt + (size_t)(i * 32) * 2048;
      const float* pb = Bg + kt + (size_t)(i * 32) * 2048;
      av[i][0] = *(const float4*)pa;
      av[i][1] = *(const float4*)(pa + 4);
      bv[i][0] = *(const float4*)pb;
      bv[i][1] = *(const float4*)(pb + 4);
    }
    __syncthreads();
#pragma unroll
    for (int i = 0; i < 4; ++i) {
      int r = srow + i * 32;
      *(bf16x8*)&As[r][scol] = pack8(av[i][0], av[i][1]);
      *(bf16x8*)&Bs[r][scol] = pack8(bv[i][0], bv[i][1]);
    }
    __syncthreads();
#pragma unroll
    for (int ks = 0; ks < 2; ++ks) {
      const int k0 = ks * 32 + ((lane >> 4) << 3);
      bf16x8 af[4], bf[4];
#pragma unroll
      for (int m = 0; m < 4; ++m)
        af[m] = *(const bf16x8*)&As[wm + m * 16 + (lane & 15)][k0];
#pragma unroll
      for (int n = 0; n < 4; ++n)
        bf[n] = *(const bf16x8*)&Bs[wn + n * 16 + (lane & 15)][k0];
#pragma unroll
      for (int m = 0; m < 4; ++m)
#pragma unroll
        for (int n = 0; n < 4; ++n)
          acc[m][n] = __builtin_amdgcn_mfma_f32_16x16x32_bf16(af[m], bf[n], acc[m][n], 0, 0, 0);
    }
  }

  const int cgrp = lane >> 4;
  const int clane = lane & 15;
#pragma unroll
  for (int m = 0; m < 4; ++m) {
#pragma unroll
    for (int r = 0; r < 4; ++r) {
      const int rl = wm + m * 16 + cgrp * 4 + r;
      float p = 0.f;
#pragma unroll
      for (int n = 0; n < 4; ++n) {
        const int cl = wn + n * 16 + clane;
        float v = acc[m][n][r] + qs[cl];
        p += fast_tanh(v) * wes[cl];
      }
      p += __shfl_xor(p, 1);
      p += __shfl_xor(p, 2);
      p += __shfl_xor(p, 4);
      p += __shfl_xor(p, 8);
      if (clane == 0) atomicAdd(&scores[mbase + rl], p);
    }
  }
}

__global__ __launch_bounds__(256) void context_partial_fb(
    const float* __restrict__ enc, const float* __restrict__ alphas,
    float* __restrict__ partial) {
  int blk = blockIdx.x;
  int sc = blk & 7;
  int ec = (blk >> 3) & 1;
  int b = blk >> 4;
  int t = threadIdx.x;
  int e0 = ec * 1024 + t * 4;
  __shared__ float al[256];
  al[t] = alphas[b * 2048 + sc * 256 + t];
  __syncthreads();
  const float* ebase = enc + (size_t)b * 2048 * 2048 + (size_t)(sc * 256) * 2048 + e0;
  f32x4 acc = {};
  for (int s = 0; s < 256; ++s) {
    float a = al[s];
    float4 v = *(const float4*)(ebase + (size_t)s * 2048);
    acc[0] += a * v.x; acc[1] += a * v.y; acc[2] += a * v.z; acc[3] += a * v.w;
  }
  *(f32x4*)(partial + ((size_t)sc * 32 + b) * 2048 + e0) = acc;
}

__global__ __launch_bounds__(256) void context_reduce_fb(const float* __restrict__ partial,
                                                         float* __restrict__ out) {
  int i = blockIdx.x * 256 + threadIdx.x;
  float s = 0.f;
#pragma unroll
  for (int sc = 0; sc < 8; ++sc) s += partial[sc * 65536 + i];
  out[i] = s;
}

extern "C" void kernel_launch(void* const* d_in, const int* in_sizes, int n_in,
                              void* d_out, int out_size, void* d_ws, size_t ws_size,
                              hipStream_t stream) {
  const float* enc = (const float*)d_in[0];  // [32, 2048, 2048]
  const float* dec = (const float*)d_in[1];  // [32, 1, 1024]
  const float* Wq = (const float*)d_in[2];   // [1024, 1024]
  const float* Wk = (const float*)d_in[3];   // [1024, 2048]
  const float* We = (const float*)d_in[4];   // [1, 1024]
  float* out = (float*)d_out;                // [32, 1, 2048]

  const size_t ABF_B = 268435456UL;  // 32*2048*2048 bf16
  const size_t BBF_B = 4194304UL;    // 1024*2048 bf16
  const size_t need = ABF_B + BBF_B + 131072UL + 262144UL + 262144UL + 16777216UL;

  if (ws_size >= need) {
    char* w = (char*)d_ws;
    __bf16* Abf = (__bf16*)w;
    __bf16* Bbf = (__bf16*)(w + ABF_B);
    float* q = (float*)(w + ABF_B + BBF_B);
    float* scores = q + 32768;
    float* alphas = scores + 65536;
    float* partial = alphas + 65536;

    hipMemsetAsync(scores, 0, 65536 * sizeof(float), stream);
    f32_to_bf16_kernel<<<65536, 256, 0, stream>>>(enc, Abf);
    f32_to_bf16_kernel<<<1024, 256, 0, stream>>>(Wk, Bbf);
    query_kernel<<<8192, 256, 0, stream>>>(dec, Wq, q);
    key_score_mfma<<<4096, 256, 0, stream>>>(Abf, Bbf, q, We, scores);
    softmax_kernel<<<32, 256, 0, stream>>>(scores, alphas);
    context_partial16_kernel<<<1024, 256, 0, stream>>>(enc, alphas, partial);
    context_reduce16_kernel<<<256, 256, 0, stream>>>(partial, out);
  } else {
    float* q = (float*)d_ws;
    float* scores = q + 32768;
    float* alphas = scores + 65536;
    float* partial = alphas + 65536;

    hipMemsetAsync(scores, 0, 65536 * sizeof(float), stream);
    query_kernel<<<8192, 256, 0, stream>>>(dec, Wq, q);
    key_score_kernel_fb<<<4096, 256, 0, stream>>>(enc, Wk, q, We, scores);
    softmax_kernel<<<32, 256, 0, stream>>>(scores, alphas);
    context_partial_fb<<<512, 256, 0, stream>>>(enc, alphas, partial);
    context_reduce_fb<<<256, 256, 0, stream>>>(partial, out);
  }
}

// Round 5
// 1037.052 us; speedup vs baseline: 1.2813x; 1.1344x over previous
//
#include <hip/hip_runtime.h>
#include <hip/hip_bf16.h>

typedef float f32x4 __attribute__((ext_vector_type(4)));
typedef __bf16 bf16x8 __attribute__((ext_vector_type(8)));

__device__ __forceinline__ float fast_tanh(float x) {
  x = fminf(fmaxf(x, -15.f), 15.f);
  float e = __expf(2.f * x);
  return (e - 1.f) / (e + 1.f);
}

__device__ __forceinline__ bf16x8 pack8(float4 a, float4 b) {
  bf16x8 r;
  r[0] = (__bf16)a.x; r[1] = (__bf16)a.y; r[2] = (__bf16)a.z; r[3] = (__bf16)a.w;
  r[4] = (__bf16)b.x; r[5] = (__bf16)b.y; r[6] = (__bf16)b.z; r[7] = (__bf16)b.w;
  return r;
}

__device__ __forceinline__ void gload_lds16(const void* g, void* l) {
  __builtin_amdgcn_global_load_lds(
      (const __attribute__((address_space(1))) unsigned int*)g,
      (__attribute__((address_space(3))) unsigned int*)l, 16, 0, 0);
}

// ---------------- query: q[b,h] = sum_e dec[b,e] * Wq[h,e] ----------------
__global__ __launch_bounds__(256) void query_kernel(const float* __restrict__ dec,
                                                    const float* __restrict__ Wq,
                                                    float* __restrict__ q) {
  int wid = threadIdx.x >> 6, lane = threadIdx.x & 63;
  int o = blockIdx.x * 4 + wid;
  int b = o >> 10, h = o & 1023;
  const float* wrow = Wq + (size_t)h * 1024;
  const float* drow = dec + (size_t)b * 1024;
  float s = 0.f;
#pragma unroll
  for (int j = 0; j < 4; ++j) {
    int e = j * 256 + lane * 4;
    float4 w = *(const float4*)(wrow + e);
    float4 d = *(const float4*)(drow + e);
    s += w.x * d.x + w.y * d.y + w.z * d.z + w.w * d.w;
  }
  for (int off = 32; off; off >>= 1) s += __shfl_xor(s, off);
  if (lane == 0) q[o] = s;
}

// ---------------- fp32 -> bf16 streaming convert ----------------
__global__ __launch_bounds__(256) void f32_to_bf16_kernel(const float* __restrict__ in,
                                                          __bf16* __restrict__ out) {
  size_t i = ((size_t)blockIdx.x * 256 + threadIdx.x) * 8;
  float4 a = *(const float4*)(in + i);
  float4 b = *(const float4*)(in + i + 4);
  *(bf16x8*)(out + i) = pack8(a, b);
}

// ==== 256^2-tile, BK=32, 4-slot LDS ring, counted-vmcnt pipelined GEMM ====
// A [65536][2048] bf16, Bw [1024][2048] bf16 (K-major, NT GEMM).
// Fused epilogue: scores[m] += sum_h tanh(key[m,h] + q[b,h]) * We[h]
__global__ __launch_bounds__(512, 2) void key_score_mfma256(
    const __bf16* __restrict__ A, const __bf16* __restrict__ Bw,
    const float* __restrict__ q, const float* __restrict__ We,
    float* __restrict__ scores) {
  // 4 slots x (A 8192 + B 8192 elems) = 65536 bf16 = 128 KiB
  __shared__ __align__(16) __bf16 lds[65536];

  const int t0 = threadIdx.x;
  const int lane = t0 & 63;
  const int wid = t0 >> 6;

  // XCD-bijective swizzle: 1024 blocks, bid%8 = XCD. XCD c owns mblks
  // [c*32, c*32+32), iterating nblk (4) fast -> A panel L2-shared by 4 blocks.
  const int bid = blockIdx.x;
  const int g = (bid & 7) * 128 + (bid >> 3);
  const int mblk = g >> 2;
  const int nblk = g & 3;
  const int mbase = mblk * 256;
  const int nbase = nblk * 256;
  const int bb = mbase >> 11;  // batch index (256 | 2048)

  // wave tile: wm in {0,128}, wn in {0,64,128,192}; per-wave out 128x64
  const int wm = (wid >> 2) << 7;
  const int wn = (wid & 3) << 6;

  // ---- staging map (pre-swizzled global source, linear LDS dest) ----
  // LDS slot-linear 16B unit s = l*512 + t0 -> row r = s>>2, chunk' = t0&3,
  // holds global chunk c = chunk' ^ ((r>>1)&3) = (t0&3)^((t0>>3)&3).
  const int rA = t0 >> 2;  // 0..127 (+128 for second load)
  const int c8 = (((t0 & 3) ^ ((t0 >> 3) & 3)) << 3);
  const __bf16* gA0 = A + (size_t)(mbase + rA) * 2048 + c8;
  const __bf16* gB0 = Bw + (size_t)(nbase + rA) * 2048 + c8;
  const int ldsw = wid * 512;  // wave-uniform LDS elem base (per load l: +l*4096)

  // ---- read-side swizzled LDS element offsets (compile-time unrolled) ----
  const int lm = lane & 15;
  const int hi = lane >> 4;
  int offA[8], offB[4];
#pragma unroll
  for (int m = 0; m < 8; ++m) {
    int R = (wm) + m * 16 + lm;
    offA[m] = R * 32 + ((hi ^ ((R >> 1) & 3)) << 3);
  }
#pragma unroll
  for (int n = 0; n < 4; ++n) {
    int R = (wn) + n * 16 + lm;
    offB[n] = 8192 + R * 32 + ((hi ^ ((R >> 1) & 3)) << 3);
  }

  f32x4 acc[8][4] = {};

#define STAGE_A(tt)                                             \
  do {                                                          \
    __bf16* d = &lds[(((tt) & 3) << 14) + ldsw];                \
    const __bf16* s = gA0 + (tt) * 32;                          \
    gload_lds16(s, d);                                          \
    gload_lds16(s + 128 * 2048, d + 4096);                      \
  } while (0)
#define STAGE_B(tt)                                             \
  do {                                                          \
    __bf16* d = &lds[(((tt) & 3) << 14) + 8192 + ldsw];         \
    const __bf16* s = gB0 + (tt) * 32;                          \
    gload_lds16(s, d);                                          \
    gload_lds16(s + 128 * 2048, d + 4096);                      \
  } while (0)

  // prologue: stage tiles 0,1; wait tile 0 (leave tile 1 in flight)
  STAGE_A(0); STAGE_B(0); STAGE_A(1); STAGE_B(1);
  asm volatile("s_waitcnt vmcnt(4)" ::: "memory");
  __builtin_amdgcn_sched_barrier(0);
  __builtin_amdgcn_s_barrier();
  __builtin_amdgcn_sched_barrier(0);

  for (int t = 0; t < 64; ++t) {
    const __bf16* sl = &lds[(t & 3) << 14];
    // ---- phase 0: A m0-3 + B n0-3, stage A(t+2), MFMA quad {m0-3 x n0-3} ----
    if (t <= 61) STAGE_A(t + 2);
    bf16x8 af[4], af2[4], bfr[4];
#pragma unroll
    for (int m = 0; m < 4; ++m) af[m] = *(const bf16x8*)&sl[offA[m]];
#pragma unroll
    for (int n = 0; n < 4; ++n) bfr[n] = *(const bf16x8*)&sl[offB[n]];
    __builtin_amdgcn_s_setprio(1);
#pragma unroll
    for (int m = 0; m < 4; ++m)
#pragma unroll
      for (int n = 0; n < 4; ++n)
        acc[m][n] = __builtin_amdgcn_mfma_f32_16x16x32_bf16(af[m], bfr[n], acc[m][n], 0, 0, 0);
    __builtin_amdgcn_s_setprio(0);
    // ---- phase 1: A m4-7, stage B(t+2), MFMA quad {m4-7 x n0-3} ----
    if (t <= 61) STAGE_B(t + 2);
#pragma unroll
    for (int m = 0; m < 4; ++m) af2[m] = *(const bf16x8*)&sl[offA[m + 4]];
    __builtin_amdgcn_s_setprio(1);
#pragma unroll
    for (int m = 0; m < 4; ++m)
#pragma unroll
      for (int n = 0; n < 4; ++n)
        acc[m + 4][n] = __builtin_amdgcn_mfma_f32_16x16x32_bf16(af2[m], bfr[n], acc[m + 4][n], 0, 0, 0);
    __builtin_amdgcn_s_setprio(0);
    // ---- tile boundary: counted vmcnt (tile t+1 ready; t+2 stays in flight) ----
    if (t < 63) {
      __builtin_amdgcn_sched_barrier(0);
      if (t <= 61) asm volatile("s_waitcnt vmcnt(4)" ::: "memory");
      else asm volatile("s_waitcnt vmcnt(0)" ::: "memory");
      __builtin_amdgcn_sched_barrier(0);
      __builtin_amdgcn_s_barrier();
      __builtin_amdgcn_sched_barrier(0);
    }
  }
#undef STAGE_A
#undef STAGE_B

  // ---- epilogue: C/D layout col = lane&15 (N), row = (lane>>4)*4+reg (M) ----
  const int cgrp = lane >> 4, clane = lane & 15;
  float qv[4], wv[4];
#pragma unroll
  for (int n = 0; n < 4; ++n) {
    int cl = nbase + wn + n * 16 + clane;
    qv[n] = q[(bb << 10) + cl];
    wv[n] = We[cl];
  }
#pragma unroll
  for (int m = 0; m < 8; ++m)
#pragma unroll
    for (int r = 0; r < 4; ++r) {
      float p = 0.f;
#pragma unroll
      for (int n = 0; n < 4; ++n)
        p += fast_tanh(acc[m][n][r] + qv[n]) * wv[n];
      p += __shfl_xor(p, 1);
      p += __shfl_xor(p, 2);
      p += __shfl_xor(p, 4);
      p += __shfl_xor(p, 8);
      if (clane == 0) atomicAdd(&scores[mbase + wm + m * 16 + cgrp * 4 + r], p);
    }
}

// ---------------- softmax over S per batch row ----------------
__global__ __launch_bounds__(256) void softmax_kernel(const float* __restrict__ scores,
                                                      float* __restrict__ alphas) {
  const float* srow = scores + blockIdx.x * 2048;
  float* arow = alphas + blockIdx.x * 2048;
  int t = threadIdx.x, lane = t & 63, wid = t >> 6;
  float v[8];
  float mx = -1e30f;
#pragma unroll
  for (int i = 0; i < 8; ++i) {
    v[i] = srow[t + i * 256];
    mx = fmaxf(mx, v[i]);
  }
  for (int off = 32; off; off >>= 1) mx = fmaxf(mx, __shfl_xor(mx, off));
  __shared__ float redm[4], reds[4];
  if (lane == 0) redm[wid] = mx;
  __syncthreads();
  mx = fmaxf(fmaxf(redm[0], redm[1]), fmaxf(redm[2], redm[3]));
  float sum = 0.f;
#pragma unroll
  for (int i = 0; i < 8; ++i) {
    v[i] = __expf(v[i] - mx);
    sum += v[i];
  }
  for (int off = 32; off; off >>= 1) sum += __shfl_xor(sum, off);
  if (lane == 0) reds[wid] = sum;
  __syncthreads();
  sum = reds[0] + reds[1] + reds[2] + reds[3];
  float inv = 1.f / sum;
#pragma unroll
  for (int i = 0; i < 8; ++i) arow[t + i * 256] = v[i] * inv;
}

// ------- context partials from bf16 enc copy (halved traffic, no atomics) -------
__global__ __launch_bounds__(256) void context_partial_bf16(
    const __bf16* __restrict__ encb, const float* __restrict__ alphas,
    float* __restrict__ partial) {
  int sc = blockIdx.x & 15, b = blockIdx.x >> 4;  // 512 = 32b x 16sc
  int t = threadIdx.x;
  __shared__ float al[128];
  if (t < 128) al[t] = alphas[b * 2048 + sc * 128 + t];
  __syncthreads();
  const __bf16* e = encb + ((size_t)b * 2048 + (size_t)sc * 128) * 2048 + t * 8;
  float acc[8] = {};
#pragma unroll 4
  for (int s = 0; s < 128; ++s) {
    float a = al[s];
    bf16x8 v = *(const bf16x8*)(e + (size_t)s * 2048);
#pragma unroll
    for (int j = 0; j < 8; ++j) acc[j] += a * (float)v[j];
  }
  float* p = partial + ((size_t)sc * 32 + b) * 2048 + (size_t)t * 8;
#pragma unroll
  for (int j = 0; j < 8; ++j) p[j] = acc[j];
}

__global__ __launch_bounds__(256) void context_reduce16_kernel(const float* __restrict__ partial,
                                                               float* __restrict__ out) {
  int i = blockIdx.x * 256 + threadIdx.x;
  float s = 0.f;
#pragma unroll
  for (int sc = 0; sc < 16; ++sc) s += partial[sc * 65536 + i];
  out[i] = s;
}

extern "C" void kernel_launch(void* const* d_in, const int* in_sizes, int n_in,
                              void* d_out, int out_size, void* d_ws, size_t ws_size,
                              hipStream_t stream) {
  const float* enc = (const float*)d_in[0];  // [32, 2048, 2048]
  const float* dec = (const float*)d_in[1];  // [32, 1, 1024]
  const float* Wq = (const float*)d_in[2];   // [1024, 1024]
  const float* Wk = (const float*)d_in[3];   // [1024, 2048]
  const float* We = (const float*)d_in[4];   // [1, 1024]
  float* out = (float*)d_out;                // [32, 1, 2048]

  const size_t ABF_B = 268435456UL;  // 32*2048*2048 bf16
  const size_t BBF_B = 4194304UL;    // 1024*2048 bf16

  char* w = (char*)d_ws;
  __bf16* Abf = (__bf16*)w;
  __bf16* Bbf = (__bf16*)(w + ABF_B);
  float* q = (float*)(w + ABF_B + BBF_B);
  float* scores = q + 32768;
  float* alphas = scores + 65536;
  float* partial = alphas + 65536;

  hipMemsetAsync(scores, 0, 65536 * sizeof(float), stream);
  f32_to_bf16_kernel<<<65536, 256, 0, stream>>>(enc, Abf);
  f32_to_bf16_kernel<<<1024, 256, 0, stream>>>(Wk, Bbf);
  query_kernel<<<8192, 256, 0, stream>>>(dec, Wq, q);
  key_score_mfma256<<<1024, 512, 0, stream>>>(Abf, Bbf, q, We, scores);
  softmax_kernel<<<32, 256, 0, stream>>>(scores, alphas);
  context_partial_bf16<<<512, 256, 0, stream>>>(Abf, alphas, partial);
  context_reduce16_kernel<<<256, 256, 0, stream>>>(partial, out);
}